// Round 19
// baseline (72.635 us; speedup 1.0000x reference)
//
#include <hip/hip_runtime.h>

// TriAffine: S[b,x,y,z] = sum_{i,k,j} xb[b,x,i] z[b,z,k] W[i,k,j] yb[b,y,j]
// B=2, L=256, N_IN=128. Output [2,256,256,256] f32 (134 MB).
//
//  stage1 : unchanged r14/r17 (W tile -> LDS T, two 128-bx sub-passes, GEMM).
//  stage2v3: r18's 2-bx pipeline + split-stage overlap:
//    issue BOTH A2 tiles' global loads up-front (regs, one exposure);
//    ds_write R0 only -> barrier -> phaseA_a (yf cached in regs);
//    R1 ds_writes retired WITH P'_a writes (behind the existing B3 barrier);
//    phaseB_a stores; phaseA_b (R1 + cached yf); P'_b->R0; phaseB_b.
//    Removes R1 staging (~1.4us) from the store-silent serial prefix.
//    1 block/CU (LDS 102.4KB), launch_bounds(512,2): 256-VGPR cap, no spill.

typedef __bf16 bf16x8 __attribute__((ext_vector_type(8)));
typedef short short4_t __attribute__((ext_vector_type(4)));
typedef float f32x4 __attribute__((ext_vector_type(4)));
typedef unsigned short ushort4_t __attribute__((ext_vector_type(4)));

#define LL 256
#define NI 128
#define NFLATP 17408           // 128 * 136 (padded (k,j) axis)
#define KJ_STRIDE 136          // j-stride within A2 row / LDS
#define XB_STRIDE 132          // x LDS i-stride (stage1)
#define P_STRIDE 132           // P' LDS k-stride (264B)
#define NCH (NFLATP / 8)       // 2176 float4 chunks per A2 tile

__device__ __forceinline__ unsigned short f2bf(float f) {
    unsigned u = __builtin_bit_cast(unsigned, f);
    u += 0x7FFFu + ((u >> 16) & 1u);   // RNE
    return (unsigned short)(u >> 16);
}
__device__ __forceinline__ float bf2f(unsigned short h) {
    return __builtin_bit_cast(float, (unsigned)h << 16);
}

// ---------------- stage1: W-stage + two-sub-pass GEMM + yz-prep (r17, unchanged) ----------------
__global__ __launch_bounds__(512, 4) void stage1_kernel(const float* __restrict__ W,
                                                        const float* __restrict__ x,
                                                        const float* __restrict__ y,
                                                        const float* __restrict__ z,
                                                        unsigned short* __restrict__ yzbf,
                                                        unsigned short* __restrict__ A2g) {
    const int blk = blockIdx.x, tid = threadIdx.x;

    if (blk >= 272) {           // ---- yz prep: 64 blocks x 512 thr x 4 elems ----
        int t = (blk - 272) * 512 + tid;
        int base = t * 4;
        int which = base >> 16;                // 0: y, 1: z
        int local = base & 65535;
        const float* s = which ? z : y;
        float4 v = *(const float4*)(s + local);
        ushort4_t o;
        o[0] = f2bf(v.x); o[1] = f2bf(v.y); o[2] = f2bf(v.z); o[3] = f2bf(v.w);
        *(ushort4_t*)(yzbf + base) = o;
        return;
    }

    __shared__ unsigned short T[128 * KJ_STRIDE];    // 34816 B
    __shared__ unsigned short XB[128 * XB_STRIDE];   // 33792 B

    const int wv = tid >> 6, lane = tid & 63;
    const int l15 = lane & 15, h = lane >> 4;

    {   // ---- W stage: T[nl][i]; all 33 loads batch-issued, j-coalesced ----
        const int nl = tid & 127, ig = tid >> 7;
        const int np = (blk >> 1) * 128 + nl;
        const int k  = np / KJ_STRIDE;
        const int j  = np - k * KJ_STRIDE;
        const bool jok = (j <= 128);
        const float* Wkj = W + (size_t)k * 129 + j;
        float wreg[33];
#pragma unroll
        for (int r = 0; r < 33; ++r) {
            int i = ig + r * 4;
            wreg[r] = (i <= 128 && jok) ? Wkj[(size_t)i * 16512] : 0.f;
        }
#pragma unroll
        for (int r = 0; r < 33; ++r) {
            int i = ig + r * 4;
            if (i <= 128) T[nl * KJ_STRIDE + i] = f2bf(wreg[r]);
        }
    }
    __syncthreads();

    const int bxg = blk & 1;
    const int nb  = blk >> 1;
    const int nloc  = wv * 16;
    const int nglob = nb * 128 + nloc;

    bf16x8 af[4];
#pragma unroll
    for (int is = 0; is < 4; ++is)
        af[is] = *(const bf16x8*)&T[(nloc + l15) * KJ_STRIDE + is * 32 + 8 * h];
    f32x4 binit;
#pragma unroll
    for (int r = 0; r < 4; ++r)
        binit[r] = bf2f(T[(nloc + 4 * h + r) * KJ_STRIDE + 128]);

#pragma unroll 1
    for (int sp = 0; sp < 2; ++sp) {
        if (sp) __syncthreads();
        const int bx0 = bxg * 256 + sp * 128;

        {
            const float* xsrc = x + (size_t)bx0 * NI;
#pragma unroll
            for (int c = 0; c < 8; ++c) {
                int idx = c * 512 + tid;
                float4 v = *(const float4*)(xsrc + (size_t)idx * 4);
                int row = idx >> 5, col = (idx & 31) * 4;
                ushort4_t o;
                o[0] = f2bf(v.x); o[1] = f2bf(v.y); o[2] = f2bf(v.z); o[3] = f2bf(v.w);
                *(ushort4_t*)&XB[row * XB_STRIDE + col] = o;
            }
        }
        __syncthreads();

        f32x4 acc[8];
#pragma unroll
        for (int ct = 0; ct < 8; ++ct) acc[ct] = binit;
#pragma unroll
        for (int is = 0; is < 4; ++is)
#pragma unroll
            for (int ct = 0; ct < 8; ++ct) {
                bf16x8 xf = *(const bf16x8*)&XB[(ct * 16 + l15) * XB_STRIDE + is * 32 + 8 * h];
                acc[ct] = __builtin_amdgcn_mfma_f32_16x16x32_bf16(af[is], xf, acc[ct], 0, 0, 0);
            }
#pragma unroll
        for (int ct = 0; ct < 8; ++ct) {
            ushort4_t o;
#pragma unroll
            for (int r = 0; r < 4; ++r) o[r] = f2bf(acc[ct][r]);
            *(ushort4_t*)(A2g + (size_t)(bx0 + ct * 16 + l15) * NFLATP + nglob + 4 * h) = o;
        }
    }
}

// ---------------- stage2v3: 2-bx pipeline with split staging, 256 blocks ----------------
__global__ __launch_bounds__(512, 2) void stage2_kernel(const unsigned short* __restrict__ ybf,
                                                        const unsigned short* __restrict__ zbf,
                                                        const unsigned short* __restrict__ A2g,
                                                        float* __restrict__ out) {
    const int blk = blockIdx.x;            // 0..255
    const int bxa = blk * 2, bxb = bxa + 1;
    const int b   = bxa >> 8;              // same b for both halves
    const int tid = threadIdx.x;
    const int wv = tid >> 6, lane = tid & 63;
    const int l15 = lane & 15, h = lane >> 4;

    __shared__ __align__(16) unsigned short SH[LL * P_STRIDE + NFLATP];  // 67584 + 34816 B
    unsigned short* R1 = SH + LL * P_STRIDE;

    // 1. issue ALL global loads for both A2 tiles (one latency exposure)
    const float4* sa = (const float4*)(A2g + (size_t)bxa * NFLATP);
    const float4* sb = (const float4*)(A2g + (size_t)bxb * NFLATP);
    float4 r0v[5], r1v[5];
#pragma unroll
    for (int c = 0; c < 5; ++c) { int t = c * 512 + tid; if (t < NCH) r0v[c] = sa[t]; }
#pragma unroll
    for (int c = 0; c < 5; ++c) { int t = c * 512 + tid; if (t < NCH) r1v[c] = sb[t]; }

    // 2. retire R0 only -> phaseA_a can start; R1 regs held
    {
        float4* d0 = (float4*)SH;
#pragma unroll
        for (int c = 0; c < 5; ++c) { int t = c * 512 + tid; if (t < NCH) d0[t] = r0v[c]; }
    }
    __syncthreads();   // B1: A2_a visible

    const unsigned short* yb = ybf + b * LL * NI;
    const unsigned short* zb = zbf + b * LL * NI;
    const int y0 = wv * 32;
    const int zg = wv & 3, yh = wv >> 2;
    const int z0 = zg * 64;

    // 3. phaseA_a (R0); y-fragments cached for reuse in phaseA_b
    bf16x8 yfs[4][2];
    f32x4 accP[8][2];
#pragma unroll
    for (int kt = 0; kt < 8; ++kt)
#pragma unroll
        for (int r = 0; r < 4; ++r) {
            float bias = bf2f(SH[(kt * 16 + 4 * h + r) * KJ_STRIDE + 128]);
            accP[kt][0][r] = bias; accP[kt][1][r] = bias;
        }
#pragma unroll
    for (int js = 0; js < 4; ++js) {
#pragma unroll
        for (int yt = 0; yt < 2; ++yt)
            yfs[js][yt] = *(const bf16x8*)(yb + (y0 + yt * 16 + l15) * NI + js * 32 + 8 * h);
#pragma unroll
        for (int kt = 0; kt < 8; ++kt) {
            bf16x8 af2 = *(const bf16x8*)&SH[(kt * 16 + l15) * KJ_STRIDE + js * 32 + 8 * h];
            accP[kt][0] = __builtin_amdgcn_mfma_f32_16x16x32_bf16(af2, yfs[js][0], accP[kt][0], 0, 0, 0);
            accP[kt][1] = __builtin_amdgcn_mfma_f32_16x16x32_bf16(af2, yfs[js][1], accP[kt][1], 0, 0, 0);
        }
    }
    __syncthreads();   // B2: A2_a reads done (R0 may be overwritten)

    // 5. P'_a -> R0; retire R1 ds_writes; zf loads (once, reused both halves)
#pragma unroll
    for (int kt = 0; kt < 8; ++kt)
#pragma unroll
        for (int yt = 0; yt < 2; ++yt) {
            unsigned lo = (unsigned)f2bf(accP[kt][yt][0]) | ((unsigned)f2bf(accP[kt][yt][1]) << 16);
            unsigned hi = (unsigned)f2bf(accP[kt][yt][2]) | ((unsigned)f2bf(accP[kt][yt][3]) << 16);
            uint2 v; v.x = lo; v.y = hi;
            *(uint2*)&SH[(y0 + yt * 16 + l15) * P_STRIDE + kt * 16 + 4 * h] = v;
        }
    {
        float4* d1 = (float4*)R1;
#pragma unroll
        for (int c = 0; c < 5; ++c) { int t = c * 512 + tid; if (t < NCH) d1[t] = r1v[c]; }
    }
    short4_t zf[4][8];
#pragma unroll
    for (int zt = 0; zt < 4; ++zt)
#pragma unroll
        for (int kt = 0; kt < 8; ++kt)
            zf[zt][kt] = *(const short4_t*)(zb + (z0 + zt * 16 + l15) * NI + kt * 16 + 4 * h);
    __syncthreads();   // B3: P'_a + A2_b visible

    // 7. phaseB_a: stores stream
    {
        float* outb = out + (size_t)bxa * (LL * LL);
#pragma unroll 1
        for (int yti = 0; yti < 8; ++yti) {
            const int yy = yh * 128 + yti * 16 + l15;
            f32x4 acc2[4];
#pragma unroll
            for (int zt = 0; zt < 4; ++zt) { acc2[zt][0] = 0.f; acc2[zt][1] = 0.f; acc2[zt][2] = 0.f; acc2[zt][3] = 0.f; }
#pragma unroll
            for (int kt = 0; kt < 8; ++kt) {
                short4_t pB = *(const short4_t*)&SH[yy * P_STRIDE + kt * 16 + 4 * h];
#pragma unroll
                for (int zt = 0; zt < 4; ++zt)
                    acc2[zt] = __builtin_amdgcn_mfma_f32_16x16x16bf16_1k(zf[zt][kt], pB, acc2[zt], 0, 0, 0);
            }
#pragma unroll
            for (int zt = 0; zt < 4; ++zt)
                *(f32x4*)(outb + (size_t)yy * LL + z0 + zt * 16 + 4 * h) = acc2[zt];
        }
    }

    // 8. phaseA_b (R1, cached yfs) -- hidden under phaseB_a's draining stores
#pragma unroll
    for (int kt = 0; kt < 8; ++kt)
#pragma unroll
        for (int r = 0; r < 4; ++r) {
            float bias = bf2f(R1[(kt * 16 + 4 * h + r) * KJ_STRIDE + 128]);
            accP[kt][0][r] = bias; accP[kt][1][r] = bias;
        }
#pragma unroll
    for (int js = 0; js < 4; ++js)
#pragma unroll
        for (int kt = 0; kt < 8; ++kt) {
            bf16x8 af2 = *(const bf16x8*)&R1[(kt * 16 + l15) * KJ_STRIDE + js * 32 + 8 * h];
            accP[kt][0] = __builtin_amdgcn_mfma_f32_16x16x32_bf16(af2, yfs[js][0], accP[kt][0], 0, 0, 0);
            accP[kt][1] = __builtin_amdgcn_mfma_f32_16x16x32_bf16(af2, yfs[js][1], accP[kt][1], 0, 0, 0);
        }
    __syncthreads();   // B4: P'_a reads done (R0 may be overwritten)

    // 10. P'_b -> R0
#pragma unroll
    for (int kt = 0; kt < 8; ++kt)
#pragma unroll
        for (int yt = 0; yt < 2; ++yt) {
            unsigned lo = (unsigned)f2bf(accP[kt][yt][0]) | ((unsigned)f2bf(accP[kt][yt][1]) << 16);
            unsigned hi = (unsigned)f2bf(accP[kt][yt][2]) | ((unsigned)f2bf(accP[kt][yt][3]) << 16);
            uint2 v; v.x = lo; v.y = hi;
            *(uint2*)&SH[(y0 + yt * 16 + l15) * P_STRIDE + kt * 16 + 4 * h] = v;
        }
    __syncthreads();   // B5: P'_b visible

    // 12. phaseB_b: stores stream (zf reused)
    {
        float* outb = out + (size_t)bxb * (LL * LL);
#pragma unroll 1
        for (int yti = 0; yti < 8; ++yti) {
            const int yy = yh * 128 + yti * 16 + l15;
            f32x4 acc2[4];
#pragma unroll
            for (int zt = 0; zt < 4; ++zt) { acc2[zt][0] = 0.f; acc2[zt][1] = 0.f; acc2[zt][2] = 0.f; acc2[zt][3] = 0.f; }
#pragma unroll
            for (int kt = 0; kt < 8; ++kt) {
                short4_t pB = *(const short4_t*)&SH[yy * P_STRIDE + kt * 16 + 4 * h];
#pragma unroll
                for (int zt = 0; zt < 4; ++zt)
                    acc2[zt] = __builtin_amdgcn_mfma_f32_16x16x16bf16_1k(zf[zt][kt], pB, acc2[zt], 0, 0, 0);
            }
#pragma unroll
            for (int zt = 0; zt < 4; ++zt)
                *(f32x4*)(outb + (size_t)yy * LL + z0 + zt * 16 + 4 * h) = acc2[zt];
        }
    }
}

extern "C" void kernel_launch(void* const* d_in, const int* in_sizes, int n_in,
                              void* d_out, int out_size, void* d_ws, size_t ws_size,
                              hipStream_t stream) {
    const float* x = (const float*)d_in[0];
    const float* y = (const float*)d_in[1];
    const float* z = (const float*)d_in[2];
    const float* W = (const float*)d_in[3];   // [129][128][129][1] = [129][16512]
    float* out = (float*)d_out;

    unsigned short* yzbf = (unsigned short*)d_ws;            // y:65536 + z:65536
    unsigned short* A2g  = yzbf + 131072;                    // 512*17408 (~17.8 MB)

    stage1_kernel<<<336, 512, 0, stream>>>(W, x, y, z, yzbf, A2g);
    stage2_kernel<<<256, 512, 0, stream>>>(yzbf, yzbf + 65536, A2g, out);
}

// Round 20
// 64.006 us; speedup vs baseline: 1.1348x; 1.1348x over previous
//
#include <hip/hip_runtime.h>

// TriAffine: S[b,x,y,z] = sum_{i,k,j} xb[b,x,i] z[b,z,k] W[i,k,j] yb[b,y,j]
// B=2, L=256, N_IN=128. Output [2,256,256,256] f32 (134 MB).
//
// FINAL (r18 structure, best measured 64.0us; r19's further prefix overlap
// regressed on VGPR pressure and was reverted).
//  stage1 : W tile -> LDS T (33-reg batch, j-coalesced); two 128-bx sub-passes
//           staging XB[128][132] then GEMM; A2[bx][n'] (n'=k*136+j).
//           T+XB = 68.6KB -> 2 blocks/CU, all 336 blocks one round.
//           Blocks 272..335: y,z f32 -> bf16.
//  stage2v2: 2-bx pipeline, 256 blocks x 512 thr, 1 block/CU (LDS 102.4KB):
//    stage A2_a->R0, A2_b->R1 (one exposure); phaseA_a; P'_a->R0; zf once;
//    phaseB_a stores; phaseA_b (reads R1 -- before the R0-protect barrier);
//    P'_b->R0; phaseB_b stores (zf reused: bx pair shares b).
//    launch_bounds(512,2): VGPR cap 256 -> accP(64)+zf(64) coexist spill-free.

typedef __bf16 bf16x8 __attribute__((ext_vector_type(8)));
typedef short short4_t __attribute__((ext_vector_type(4)));
typedef float f32x4 __attribute__((ext_vector_type(4)));
typedef unsigned short ushort4_t __attribute__((ext_vector_type(4)));

#define LL 256
#define NI 128
#define NFLATP 17408           // 128 * 136 (padded (k,j) axis)
#define KJ_STRIDE 136          // j-stride within A2 row / LDS
#define XB_STRIDE 132          // x LDS i-stride (stage1)
#define P_STRIDE 132           // P' LDS k-stride (264B)

__device__ __forceinline__ unsigned short f2bf(float f) {
    unsigned u = __builtin_bit_cast(unsigned, f);
    u += 0x7FFFu + ((u >> 16) & 1u);   // RNE
    return (unsigned short)(u >> 16);
}
__device__ __forceinline__ float bf2f(unsigned short h) {
    return __builtin_bit_cast(float, (unsigned)h << 16);
}

// ---------------- stage1: W-stage + two-sub-pass GEMM + yz-prep ----------------
__global__ __launch_bounds__(512, 4) void stage1_kernel(const float* __restrict__ W,
                                                        const float* __restrict__ x,
                                                        const float* __restrict__ y,
                                                        const float* __restrict__ z,
                                                        unsigned short* __restrict__ yzbf,
                                                        unsigned short* __restrict__ A2g) {
    const int blk = blockIdx.x, tid = threadIdx.x;

    if (blk >= 272) {           // ---- yz prep: 64 blocks x 512 thr x 4 elems ----
        int t = (blk - 272) * 512 + tid;
        int base = t * 4;
        int which = base >> 16;                // 0: y, 1: z
        int local = base & 65535;
        const float* s = which ? z : y;
        float4 v = *(const float4*)(s + local);
        ushort4_t o;
        o[0] = f2bf(v.x); o[1] = f2bf(v.y); o[2] = f2bf(v.z); o[3] = f2bf(v.w);
        *(ushort4_t*)(yzbf + base) = o;
        return;
    }

    __shared__ unsigned short T[128 * KJ_STRIDE];    // 34816 B
    __shared__ unsigned short XB[128 * XB_STRIDE];   // 33792 B

    const int wv = tid >> 6, lane = tid & 63;
    const int l15 = lane & 15, h = lane >> 4;

    {   // ---- W stage: T[nl][i]; all 33 loads batch-issued, j-coalesced ----
        const int nl = tid & 127, ig = tid >> 7;
        const int np = (blk >> 1) * 128 + nl;
        const int k  = np / KJ_STRIDE;
        const int j  = np - k * KJ_STRIDE;
        const bool jok = (j <= 128);
        const float* Wkj = W + (size_t)k * 129 + j;
        float wreg[33];
#pragma unroll
        for (int r = 0; r < 33; ++r) {
            int i = ig + r * 4;
            wreg[r] = (i <= 128 && jok) ? Wkj[(size_t)i * 16512] : 0.f;
        }
#pragma unroll
        for (int r = 0; r < 33; ++r) {
            int i = ig + r * 4;
            if (i <= 128) T[nl * KJ_STRIDE + i] = f2bf(wreg[r]);
        }
    }
    __syncthreads();

    const int bxg = blk & 1;
    const int nb  = blk >> 1;
    const int nloc  = wv * 16;
    const int nglob = nb * 128 + nloc;

    bf16x8 af[4];
#pragma unroll
    for (int is = 0; is < 4; ++is)
        af[is] = *(const bf16x8*)&T[(nloc + l15) * KJ_STRIDE + is * 32 + 8 * h];
    f32x4 binit;
#pragma unroll
    for (int r = 0; r < 4; ++r)
        binit[r] = bf2f(T[(nloc + 4 * h + r) * KJ_STRIDE + 128]);

#pragma unroll 1
    for (int sp = 0; sp < 2; ++sp) {
        if (sp) __syncthreads();
        const int bx0 = bxg * 256 + sp * 128;

        {
            const float* xsrc = x + (size_t)bx0 * NI;
#pragma unroll
            for (int c = 0; c < 8; ++c) {
                int idx = c * 512 + tid;
                float4 v = *(const float4*)(xsrc + (size_t)idx * 4);
                int row = idx >> 5, col = (idx & 31) * 4;
                ushort4_t o;
                o[0] = f2bf(v.x); o[1] = f2bf(v.y); o[2] = f2bf(v.z); o[3] = f2bf(v.w);
                *(ushort4_t*)&XB[row * XB_STRIDE + col] = o;
            }
        }
        __syncthreads();

        f32x4 acc[8];
#pragma unroll
        for (int ct = 0; ct < 8; ++ct) acc[ct] = binit;
#pragma unroll
        for (int is = 0; is < 4; ++is)
#pragma unroll
            for (int ct = 0; ct < 8; ++ct) {
                bf16x8 xf = *(const bf16x8*)&XB[(ct * 16 + l15) * XB_STRIDE + is * 32 + 8 * h];
                acc[ct] = __builtin_amdgcn_mfma_f32_16x16x32_bf16(af[is], xf, acc[ct], 0, 0, 0);
            }
#pragma unroll
        for (int ct = 0; ct < 8; ++ct) {
            ushort4_t o;
#pragma unroll
            for (int r = 0; r < 4; ++r) o[r] = f2bf(acc[ct][r]);
            *(ushort4_t*)(A2g + (size_t)(bx0 + ct * 16 + l15) * NFLATP + nglob + 4 * h) = o;
        }
    }
}

// ---------------- stage2v2: 2-bx pipeline, 256 blocks, 1 block/CU ----------------
__global__ __launch_bounds__(512, 2) void stage2_kernel(const unsigned short* __restrict__ ybf,
                                                        const unsigned short* __restrict__ zbf,
                                                        const unsigned short* __restrict__ A2g,
                                                        float* __restrict__ out) {
    const int blk = blockIdx.x;            // 0..255
    const int bxa = blk * 2, bxb = bxa + 1;
    const int b   = bxa >> 8;              // same b for both
    const int tid = threadIdx.x;
    const int wv = tid >> 6, lane = tid & 63;
    const int l15 = lane & 15, h = lane >> 4;

    __shared__ __align__(16) unsigned short SH[LL * P_STRIDE + NFLATP];  // 67584 + 34816 B
    unsigned short* R1 = SH + LL * P_STRIDE;                              // A2_b buffer

    {   // stage BOTH A2 tiles up-front (single latency exposure)
        const float4* sa = (const float4*)(A2g + (size_t)bxa * NFLATP);
        const float4* sb = (const float4*)(A2g + (size_t)bxb * NFLATP);
        float4* d0 = (float4*)SH;
        float4* d1 = (float4*)R1;
        for (int t = tid; t < NFLATP / 8; t += 512) d0[t] = sa[t];
        for (int t = tid; t < NFLATP / 8; t += 512) d1[t] = sb[t];
    }
    __syncthreads();

    const unsigned short* yb = ybf + b * LL * NI;
    const unsigned short* zb = zbf + b * LL * NI;
    const int y0 = wv * 32;
    const int zg = wv & 3, yh = wv >> 2;
    const int z0 = zg * 64;

    // ======== half A: phaseA from R0 ========
    f32x4 accP[8][2];
#pragma unroll
    for (int kt = 0; kt < 8; ++kt)
#pragma unroll
        for (int r = 0; r < 4; ++r) {
            float bias = bf2f(SH[(kt * 16 + 4 * h + r) * KJ_STRIDE + 128]);
            accP[kt][0][r] = bias; accP[kt][1][r] = bias;
        }
#pragma unroll
    for (int js = 0; js < 4; ++js) {
        bf16x8 yf[2];
#pragma unroll
        for (int yt = 0; yt < 2; ++yt)
            yf[yt] = *(const bf16x8*)(yb + (y0 + yt * 16 + l15) * NI + js * 32 + 8 * h);
#pragma unroll
        for (int kt = 0; kt < 8; ++kt) {
            bf16x8 af2 = *(const bf16x8*)&SH[(kt * 16 + l15) * KJ_STRIDE + js * 32 + 8 * h];
            accP[kt][0] = __builtin_amdgcn_mfma_f32_16x16x32_bf16(af2, yf[0], accP[kt][0], 0, 0, 0);
            accP[kt][1] = __builtin_amdgcn_mfma_f32_16x16x32_bf16(af2, yf[1], accP[kt][1], 0, 0, 0);
        }
    }
    __syncthreads();   // R0 A2 reads done

    // P'_a -> R0; zf loaded once for BOTH halves (same b)
#pragma unroll
    for (int kt = 0; kt < 8; ++kt)
#pragma unroll
        for (int yt = 0; yt < 2; ++yt) {
            unsigned lo = (unsigned)f2bf(accP[kt][yt][0]) | ((unsigned)f2bf(accP[kt][yt][1]) << 16);
            unsigned hi = (unsigned)f2bf(accP[kt][yt][2]) | ((unsigned)f2bf(accP[kt][yt][3]) << 16);
            uint2 v; v.x = lo; v.y = hi;
            *(uint2*)&SH[(y0 + yt * 16 + l15) * P_STRIDE + kt * 16 + 4 * h] = v;
        }
    short4_t zf[4][8];
#pragma unroll
    for (int zt = 0; zt < 4; ++zt)
#pragma unroll
        for (int kt = 0; kt < 8; ++kt)
            zf[zt][kt] = *(const short4_t*)(zb + (z0 + zt * 16 + l15) * NI + kt * 16 + 4 * h);
    __syncthreads();   // P'_a visible

    // phaseB_a: stores stream
    {
        float* outb = out + (size_t)bxa * (LL * LL);
#pragma unroll 1
        for (int yti = 0; yti < 8; ++yti) {
            const int yy = yh * 128 + yti * 16 + l15;
            f32x4 acc2[4];
#pragma unroll
            for (int zt = 0; zt < 4; ++zt) { acc2[zt][0] = 0.f; acc2[zt][1] = 0.f; acc2[zt][2] = 0.f; acc2[zt][3] = 0.f; }
#pragma unroll
            for (int kt = 0; kt < 8; ++kt) {
                short4_t pB = *(const short4_t*)&SH[yy * P_STRIDE + kt * 16 + 4 * h];
#pragma unroll
                for (int zt = 0; zt < 4; ++zt)
                    acc2[zt] = __builtin_amdgcn_mfma_f32_16x16x16bf16_1k(zf[zt][kt], pB, acc2[zt], 0, 0, 0);
            }
#pragma unroll
            for (int zt = 0; zt < 4; ++zt)
                *(f32x4*)(outb + (size_t)yy * LL + z0 + zt * 16 + 4 * h) = acc2[zt];
        }
    }

    // ======== half B: phaseA from R1 (no barrier needed yet: R0 untouched) ========
#pragma unroll
    for (int kt = 0; kt < 8; ++kt)
#pragma unroll
        for (int r = 0; r < 4; ++r) {
            float bias = bf2f(R1[(kt * 16 + 4 * h + r) * KJ_STRIDE + 128]);
            accP[kt][0][r] = bias; accP[kt][1][r] = bias;
        }
#pragma unroll
    for (int js = 0; js < 4; ++js) {
        bf16x8 yf[2];
#pragma unroll
        for (int yt = 0; yt < 2; ++yt)
            yf[yt] = *(const bf16x8*)(yb + (y0 + yt * 16 + l15) * NI + js * 32 + 8 * h);
#pragma unroll
        for (int kt = 0; kt < 8; ++kt) {
            bf16x8 af2 = *(const bf16x8*)&R1[(kt * 16 + l15) * KJ_STRIDE + js * 32 + 8 * h];
            accP[kt][0] = __builtin_amdgcn_mfma_f32_16x16x32_bf16(af2, yf[0], accP[kt][0], 0, 0, 0);
            accP[kt][1] = __builtin_amdgcn_mfma_f32_16x16x32_bf16(af2, yf[1], accP[kt][1], 0, 0, 0);
        }
    }
    __syncthreads();   // all waves done reading P'_a (R0) -- safe to overwrite

    // P'_b -> R0
#pragma unroll
    for (int kt = 0; kt < 8; ++kt)
#pragma unroll
        for (int yt = 0; yt < 2; ++yt) {
            unsigned lo = (unsigned)f2bf(accP[kt][yt][0]) | ((unsigned)f2bf(accP[kt][yt][1]) << 16);
            unsigned hi = (unsigned)f2bf(accP[kt][yt][2]) | ((unsigned)f2bf(accP[kt][yt][3]) << 16);
            uint2 v; v.x = lo; v.y = hi;
            *(uint2*)&SH[(y0 + yt * 16 + l15) * P_STRIDE + kt * 16 + 4 * h] = v;
        }
    __syncthreads();   // P'_b visible

    // phaseB_b: stores stream (zf reused)
    {
        float* outb = out + (size_t)bxb * (LL * LL);
#pragma unroll 1
        for (int yti = 0; yti < 8; ++yti) {
            const int yy = yh * 128 + yti * 16 + l15;
            f32x4 acc2[4];
#pragma unroll
            for (int zt = 0; zt < 4; ++zt) { acc2[zt][0] = 0.f; acc2[zt][1] = 0.f; acc2[zt][2] = 0.f; acc2[zt][3] = 0.f; }
#pragma unroll
            for (int kt = 0; kt < 8; ++kt) {
                short4_t pB = *(const short4_t*)&SH[yy * P_STRIDE + kt * 16 + 4 * h];
#pragma unroll
                for (int zt = 0; zt < 4; ++zt)
                    acc2[zt] = __builtin_amdgcn_mfma_f32_16x16x16bf16_1k(zf[zt][kt], pB, acc2[zt], 0, 0, 0);
            }
#pragma unroll
            for (int zt = 0; zt < 4; ++zt)
                *(f32x4*)(outb + (size_t)yy * LL + z0 + zt * 16 + 4 * h) = acc2[zt];
        }
    }
}

extern "C" void kernel_launch(void* const* d_in, const int* in_sizes, int n_in,
                              void* d_out, int out_size, void* d_ws, size_t ws_size,
                              hipStream_t stream) {
    const float* x = (const float*)d_in[0];
    const float* y = (const float*)d_in[1];
    const float* z = (const float*)d_in[2];
    const float* W = (const float*)d_in[3];   // [129][128][129][1] = [129][16512]
    float* out = (float*)d_out;

    unsigned short* yzbf = (unsigned short*)d_ws;            // y:65536 + z:65536
    unsigned short* A2g  = yzbf + 131072;                    // 512*17408 (~17.8 MB)

    stage1_kernel<<<336, 512, 0, stream>>>(W, x, y, z, yzbf, A2g);
    stage2_kernel<<<256, 512, 0, stream>>>(yzbf, yzbf + 65536, A2g, out);
}